// Round 7
// baseline (1048.054 us; speedup 1.0000x reference)
//
#include <hip/hip_runtime.h>

#define NN   12288
#define FIN  256
#define FOUT 128
#define ALPHA 0.2f

typedef __attribute__((ext_vector_type(8))) _Float16 half8v;
typedef __attribute__((ext_vector_type(4))) float float4v;
typedef __attribute__((ext_vector_type(4))) int   int4v;

// WhT2 layout: [node>>5][feat 0..127][node&31]  (_Float16)
//   -> one j-tile (32 nodes x 128 feats) is a contiguous 8 KB block;
//      a wave's 8 B-fragment loads are each a coalesced 1 KB slice of it.

// ---------------------------------------------------------------------------
// Kernel 1: Wh = h @ W (fp32): WhT2 (f16 j-tiled) + Wh1/Wh2 (fp32) +
// per-block max of Wh2 -> mxArr[blockIdx]. One block = 16 nodes, 128 threads
// (thread t owns feature t). h is read with wave-uniform addresses (scalar-
// cache path; the old LDS tile made this kernel ds_read-throughput-bound).
// ---------------------------------------------------------------------------
__global__ __launch_bounds__(128) void k_wh(
    const float* __restrict__ h,
    const float* __restrict__ W,
    const float* __restrict__ a,
    _Float16* __restrict__ WhT2,
    float* __restrict__ Wh1, float* __restrict__ Wh2,
    float* __restrict__ mxArr)
{
    __shared__ float sP1[2][16], sP2[2][16];
    const int t = threadIdx.x;                     // 0..127
    const int row0 = blockIdx.x * 16;

    float acc[16];
    #pragma unroll
    for (int r = 0; r < 16; ++r) acc[r] = 0.f;

    const float* hb = h + (size_t)row0 * FIN;
    for (int k = 0; k < FIN; k += 4) {
        const float w0 = W[(k + 0) * FOUT + t];
        const float w1 = W[(k + 1) * FOUT + t];
        const float w2 = W[(k + 2) * FOUT + t];
        const float w3 = W[(k + 3) * FOUT + t];
        #pragma unroll
        for (int r = 0; r < 16; ++r) {
            const float4v hv = *(const float4v*)(hb + r * FIN + k);  // uniform
            float s = acc[r];
            s = fmaf(hv.x, w0, s);
            s = fmaf(hv.y, w1, s);
            s = fmaf(hv.z, w2, s);
            s = fmaf(hv.w, w3, s);
            acc[r] = s;
        }
    }

    half8v pk0, pk1;
    #pragma unroll
    for (int r = 0; r < 8; ++r)  pk0[r] = (_Float16)acc[r];
    #pragma unroll
    for (int r = 0; r < 8; ++r)  pk1[r] = (_Float16)acc[8 + r];
    _Float16* dst = WhT2 + (size_t)(row0 >> 5) * 4096 + t * 32 + (row0 & 16);
    *(half8v*)(dst)     = pk0;
    *(half8v*)(dst + 8) = pk1;

    const float a1t = a[t];
    const float a2t = a[FOUT + t];
    const int lane = t & 63, wv = t >> 6;
    #pragma unroll
    for (int r = 0; r < 16; ++r) {
        float v1 = acc[r] * a1t;
        float v2 = acc[r] * a2t;
        #pragma unroll
        for (int off = 1; off < 64; off <<= 1) {
            v1 += __shfl_xor(v1, off, 64);
            v2 += __shfl_xor(v2, off, 64);
        }
        if (lane == 0) { sP1[wv][r] = v1; sP2[wv][r] = v2; }
    }
    __syncthreads();
    if (t < 16) {
        const float v1 = sP1[0][t] + sP1[1][t];
        float v2 = sP2[0][t] + sP2[1][t];
        Wh1[row0 + t] = v1;
        Wh2[row0 + t] = v2;
        #pragma unroll
        for (int off = 1; off < 16; off <<= 1)
            v2 = fmaxf(v2, __shfl_xor(v2, off, 64));
        if (t == 0) mxArr[blockIdx.x] = v2;
    }
}

// ---------------------------------------------------------------------------
// P-fragment builder: leaky -> mask -> exp(e-M); f16 numerator, f32 row sum.
// ---------------------------------------------------------------------------
static __device__ __forceinline__ half8v build_p(
    const int4v a0, const int4v a1, const float* wvv,
    const float wh1, const float M, float& S)
{
    const int av[8] = {a0.x, a0.y, a0.z, a0.w, a1.x, a1.y, a1.z, a1.w};
    half8v af;
    #pragma unroll
    for (int jj = 0; jj < 8; ++jj) {
        float e = wh1 + wvv[jj];
        e = fmaxf(e, ALPHA * e);
        const float p = av[jj] ? __expf(e - M) : 0.f;
        af[jj] = (_Float16)p;
        S += p;
    }
    return af;
}

// global max over per-block maxima (nmx entries), block-wide.
static __device__ __forceinline__ float block_gmax(
    const float* __restrict__ mxArr, int nmx, float* smax)
{
    const int tid = threadIdx.x;
    float mv = -1e30f;
    for (int idx = tid; idx < nmx; idx += 256) mv = fmaxf(mv, mxArr[idx]);
    #pragma unroll
    for (int off = 1; off < 64; off <<= 1) mv = fmaxf(mv, __shfl_xor(mv, off, 64));
    if ((tid & 63) == 0) smax[tid >> 6] = mv;
    __syncthreads();
    return fmaxf(fmaxf(smax[0], smax[1]), fmaxf(smax[2], smax[3]));
}

// ---------------------------------------------------------------------------
// Kernel 2: fused masked-softmax attention + PV GEMM (partials).
// Grid (NN/64, J). Block = 4 waves, each wave owns 16 rows and free-runs
// over its j-slice — NO LDS staging, NO __syncthreads in the loop (the
// barrier-lockstep structure capped the memory port at ~45% duty; this is
// the restructure). WhT2 tile reuse across waves is served by L1 (8 KB
// tiles, coalesced 1 KB fragment loads). adj is nontemporal (zero reuse).
// Mi = leaky(Wh1_i + max_j Wh2_j) >= row max => exp<=1, single pass.
// Writes UN-normalized partial C + S; k_reduce finishes.
// ---------------------------------------------------------------------------
__global__ __launch_bounds__(256, 3) void k_attn(
    const int* __restrict__ adj,
    const _Float16* __restrict__ WhT2,
    const float* __restrict__ Wh1, const float* __restrict__ Wh2,
    const float* __restrict__ mxArr, int nmx,
    float* __restrict__ pC, float* __restrict__ pS)
{
    __shared__ float smax[4];
    const int tid  = threadIdx.x;
    const int w    = tid >> 6;
    const int lane = tid & 63;
    const int m    = lane & 15;
    const int q    = lane >> 4;
    const int rowbase = blockIdx.x * 64 + w * 16;
    const int J    = gridDim.y;
    const int jy   = blockIdx.y;
    const int jlen = NN / J;
    const int jbeg = jy * jlen;

    const float mxv = block_gmax(mxArr, nmx, smax);

    const float wh1 = Wh1[rowbase + m];
    const float tm  = wh1 + mxv;
    const float Mi  = fmaxf(tm, ALPHA * tm);
    const int* rowA = adj + (size_t)(rowbase + m) * NN;

    float4v c[8];
    #pragma unroll
    for (int t = 0; t < 8; ++t) c[t] = (float4v){0.f, 0.f, 0.f, 0.f};
    float S = 0.f;

    for (int j0 = jbeg; j0 < jbeg + jlen; j0 += 32) {
        const int jb = j0 + q * 8;
        const int4v a0 = __builtin_nontemporal_load((const int4v*)(rowA + jb));
        const int4v a1 = __builtin_nontemporal_load((const int4v*)(rowA + jb + 4));
        const float4v w0 = *(const float4v*)(Wh2 + jb);
        const float4v w1 = *(const float4v*)(Wh2 + jb + 4);
        const float wvv[8] = {w0.x, w0.y, w0.z, w0.w, w1.x, w1.y, w1.z, w1.w};

        const half8v af = build_p(a0, a1, wvv, wh1, Mi, S);

        const _Float16* tp = WhT2 + (size_t)(j0 >> 5) * 4096;
        #pragma unroll
        for (int t = 0; t < 8; ++t) {
            const half8v b = *(const half8v*)(tp + (t * 16 + m) * 32 + q * 8);
            c[t] = __builtin_amdgcn_mfma_f32_16x16x32_f16(af, b, c[t], 0, 0, 0);
        }
    }

    S += __shfl_xor(S, 16, 64);
    S += __shfl_xor(S, 32, 64);
    if (q == 0) pS[(size_t)jy * NN + rowbase + m] = S;

    #pragma unroll
    for (int t = 0; t < 8; ++t)
        #pragma unroll
        for (int reg = 0; reg < 4; ++reg) {
            const int row = rowbase + q * 4 + reg;
            pC[((size_t)jy * NN + row) * FOUT + t * 16 + m] = c[t][reg];
        }
}

// ---------------------------------------------------------------------------
// Kernel 3: reduce J partials, normalize, ELU.
// ---------------------------------------------------------------------------
__global__ __launch_bounds__(256) void k_reduce(
    const float* __restrict__ pC, const float* __restrict__ pS,
    float* __restrict__ out, int J)
{
    const int idx = blockIdx.x * 256 + threadIdx.x;  // (row, col/4)
    const int row = idx >> 5;
    const int c4  = (idx & 31) * 4;
    float4v acc = (float4v){0.f, 0.f, 0.f, 0.f};
    float S = 0.f;
    for (int j = 0; j < J; ++j) {
        const float4v v = *(const float4v*)(pC + ((size_t)j * NN + row) * FOUT + c4);
        acc.x += v.x; acc.y += v.y; acc.z += v.z; acc.w += v.w;
        S += pS[(size_t)j * NN + row];
    }
    const float inv = 1.f / fmaxf(S, 1e-30f);
    float4v r;
    #pragma unroll
    for (int k = 0; k < 4; ++k) {
        const float v = acc[k] * inv;
        r[k] = (v > 0.f) ? v : (__expf(v) - 1.f);
    }
    *(float4v*)(out + (size_t)row * FOUT + c4) = r;
}

// ---------------------------------------------------------------------------
// Fallback (tiny ws): barrier-free single pass, writes out directly.
// ---------------------------------------------------------------------------
__global__ __launch_bounds__(256, 3) void k_attn_fb(
    const int* __restrict__ adj,
    const _Float16* __restrict__ WhT2,
    const float* __restrict__ Wh1, const float* __restrict__ Wh2,
    const float* __restrict__ mxArr, int nmx,
    float* __restrict__ out)
{
    __shared__ float smax[4];
    const int tid  = threadIdx.x;
    const int w    = tid >> 6;
    const int lane = tid & 63;
    const int m    = lane & 15;
    const int q    = lane >> 4;
    const int rowbase = blockIdx.x * 64 + w * 16;

    const float mxv = block_gmax(mxArr, nmx, smax);

    const float wh1 = Wh1[rowbase + m];
    const float tm  = wh1 + mxv;
    const float Mi  = fmaxf(tm, ALPHA * tm);
    const int* rowA = adj + (size_t)(rowbase + m) * NN;

    float4v c[8];
    #pragma unroll
    for (int t = 0; t < 8; ++t) c[t] = (float4v){0.f, 0.f, 0.f, 0.f};
    float S = 0.f;

    for (int j0 = 0; j0 < NN; j0 += 32) {
        const int jb = j0 + q * 8;
        const int4v a0 = __builtin_nontemporal_load((const int4v*)(rowA + jb));
        const int4v a1 = __builtin_nontemporal_load((const int4v*)(rowA + jb + 4));
        const float4v w0 = *(const float4v*)(Wh2 + jb);
        const float4v w1 = *(const float4v*)(Wh2 + jb + 4);
        const float wvv[8] = {w0.x, w0.y, w0.z, w0.w, w1.x, w1.y, w1.z, w1.w};
        const half8v af = build_p(a0, a1, wvv, wh1, Mi, S);
        const _Float16* tp = WhT2 + (size_t)(j0 >> 5) * 4096;
        #pragma unroll
        for (int t = 0; t < 8; ++t) {
            const half8v b = *(const half8v*)(tp + (t * 16 + m) * 32 + q * 8);
            c[t] = __builtin_amdgcn_mfma_f32_16x16x32_f16(af, b, c[t], 0, 0, 0);
        }
    }
    S += __shfl_xor(S, 16, 64);
    S += __shfl_xor(S, 32, 64);
    #pragma unroll
    for (int reg = 0; reg < 4; ++reg) {
        const int mloc = q * 4 + reg;
        const float Sr = __shfl(S, mloc, 64);
        const float inv = 1.f / fmaxf(Sr, 1e-30f);
        #pragma unroll
        for (int t = 0; t < 8; ++t) {
            const float v = c[t][reg] * inv;
            out[(size_t)(rowbase + mloc) * FOUT + t * 16 + m] =
                (v > 0.f) ? v : (__expf(v) - 1.f);
        }
    }
}

// ---------------------------------------------------------------------------
extern "C" void kernel_launch(void* const* d_in, const int* in_sizes, int n_in,
                              void* d_out, int out_size, void* d_ws, size_t ws_size,
                              hipStream_t stream) {
    const float* h   = (const float*)d_in[0];
    const int*   adj = (const int*)d_in[1];
    const float* W   = (const float*)d_in[2];
    const float* a   = (const float*)d_in[3];
    float* out = (float*)d_out;

    char* ws = (char*)d_ws;
    float* Wh1   = (float*)ws;                          // 49152
    float* Wh2   = (float*)(ws + 49152);                // 49152
    float* mxArr = (float*)(ws + 98304);                // 768*4 = 3072
    _Float16* WhT2 = (_Float16*)(ws + 101376);          // 3,145,728
    const size_t base_need = 101376ULL + 3145728ULL;    // 3,247,104
    const int NB = NN / 16;                             // 768 k_wh blocks

    int J = 8;
    while (J > 1 &&
           base_need + (size_t)J * NN * 4 + (size_t)J * NN * FOUT * 4 > ws_size)
        J >>= 1;
    const bool ok =
        base_need + (size_t)NN * 4 + (size_t)NN * FOUT * 4 <= ws_size;

    k_wh<<<NB, 128, 0, stream>>>(h, W, a, WhT2, Wh1, Wh2, mxArr);
    if (ok) {
        float* pS = (float*)(ws + base_need);
        float* pC = pS + (size_t)J * NN;
        k_attn<<<dim3(NN / 64, J), 256, 0, stream>>>(adj, WhT2, Wh1, Wh2,
                                                     mxArr, NB, pC, pS);
        k_reduce<<<(NN * (FOUT / 4)) / 256, 256, 0, stream>>>(pC, pS, out, J);
    } else {
        k_attn_fb<<<NN / 64, 256, 0, stream>>>(adj, WhT2, Wh1, Wh2, mxArr, NB, out);
    }
}

// Round 8
// 1015.881 us; speedup vs baseline: 1.0317x; 1.0317x over previous
//
#include <hip/hip_runtime.h>

#define NN   12288
#define FIN  256
#define FOUT 128
#define ALPHA 0.2f

typedef __attribute__((ext_vector_type(8))) _Float16 half8v;
typedef __attribute__((ext_vector_type(4))) float float4v;
typedef __attribute__((ext_vector_type(4))) int   int4v;

// WhT2 layout: [node>>5][feat 0..127][node&31]  (_Float16)
//   -> one j-tile (32 nodes x 128 feats) is a contiguous 8 KB block;
//      a wave's 8 B-fragment loads are each a coalesced 1 KB slice of it.

// ---------------------------------------------------------------------------
// Kernel 1: Wh = h @ W (fp32): WhT2 (f16 j-tiled) + Wh1/Wh2 (fp32) +
// per-block max of Wh2 -> mxArr[blockIdx]. One block = 16 nodes, 128 threads.
// ---------------------------------------------------------------------------
__global__ __launch_bounds__(128) void k_wh(
    const float* __restrict__ h,
    const float* __restrict__ W,
    const float* __restrict__ a,
    _Float16* __restrict__ WhT2,
    float* __restrict__ Wh1, float* __restrict__ Wh2,
    float* __restrict__ mxArr)
{
    __shared__ float sP1[2][16], sP2[2][16];
    const int t = threadIdx.x;                     // 0..127
    const int row0 = blockIdx.x * 16;

    float acc[16];
    #pragma unroll
    for (int r = 0; r < 16; ++r) acc[r] = 0.f;

    const float* hb = h + (size_t)row0 * FIN;
    for (int k = 0; k < FIN; k += 4) {
        const float w0 = W[(k + 0) * FOUT + t];
        const float w1 = W[(k + 1) * FOUT + t];
        const float w2 = W[(k + 2) * FOUT + t];
        const float w3 = W[(k + 3) * FOUT + t];
        #pragma unroll
        for (int r = 0; r < 16; ++r) {
            const float4v hv = *(const float4v*)(hb + r * FIN + k);  // uniform
            float s = acc[r];
            s = fmaf(hv.x, w0, s);
            s = fmaf(hv.y, w1, s);
            s = fmaf(hv.z, w2, s);
            s = fmaf(hv.w, w3, s);
            acc[r] = s;
        }
    }

    half8v pk0, pk1;
    #pragma unroll
    for (int r = 0; r < 8; ++r)  pk0[r] = (_Float16)acc[r];
    #pragma unroll
    for (int r = 0; r < 8; ++r)  pk1[r] = (_Float16)acc[8 + r];
    _Float16* dst = WhT2 + (size_t)(row0 >> 5) * 4096 + t * 32 + (row0 & 16);
    *(half8v*)(dst)     = pk0;
    *(half8v*)(dst + 8) = pk1;

    const float a1t = a[t];
    const float a2t = a[FOUT + t];
    const int lane = t & 63, wv = t >> 6;
    #pragma unroll
    for (int r = 0; r < 16; ++r) {
        float v1 = acc[r] * a1t;
        float v2 = acc[r] * a2t;
        #pragma unroll
        for (int off = 1; off < 64; off <<= 1) {
            v1 += __shfl_xor(v1, off, 64);
            v2 += __shfl_xor(v2, off, 64);
        }
        if (lane == 0) { sP1[wv][r] = v1; sP2[wv][r] = v2; }
    }
    __syncthreads();
    if (t < 16) {
        const float v1 = sP1[0][t] + sP1[1][t];
        float v2 = sP2[0][t] + sP2[1][t];
        Wh1[row0 + t] = v1;
        Wh2[row0 + t] = v2;
        #pragma unroll
        for (int off = 1; off < 16; off <<= 1)
            v2 = fmaxf(v2, __shfl_xor(v2, off, 64));
        if (t == 0) mxArr[blockIdx.x] = v2;
    }
}

// ---------------------------------------------------------------------------
// P-fragment builder: leaky -> mask -> exp(e-M); f16 numerator, f32 row sum.
// ---------------------------------------------------------------------------
static __device__ __forceinline__ half8v build_p(
    const int4v a0, const int4v a1, const float* wvv,
    const float wh1, const float M, float& S)
{
    const int av[8] = {a0.x, a0.y, a0.z, a0.w, a1.x, a1.y, a1.z, a1.w};
    half8v af;
    #pragma unroll
    for (int jj = 0; jj < 8; ++jj) {
        float e = wh1 + wvv[jj];
        e = fmaxf(e, ALPHA * e);
        const float p = av[jj] ? __expf(e - M) : 0.f;
        af[jj] = (_Float16)p;
        S += p;
    }
    return af;
}

// wave-level global max over per-block maxima (single-wave block, no LDS)
static __device__ __forceinline__ float wave_gmax(
    const float* __restrict__ mxArr, int nmx, int lane)
{
    float mv = -1e30f;
    for (int idx = lane; idx < nmx; idx += 64) mv = fmaxf(mv, mxArr[idx]);
    #pragma unroll
    for (int off = 1; off < 64; off <<= 1)
        mv = fmaxf(mv, __shfl_xor(mv, off, 64));
    return mv;
}

// ---------------------------------------------------------------------------
// Kernel 2: fused masked-softmax attention + PV GEMM (partials).
// Grid (NN/64, J); block = ONE wave (64 threads), no LDS, no barriers.
// The wave owns 64 rows as 4 row-groups of 16; the 8 B-fragments (32 VGPRs)
// are loaded ONCE per 32-j tile and reused by all 4 row-groups' MFMAs —
// register-level reuse replaces round 6's LDS share (R7 lesson: dropping
// that share 8x'd WhT2 traffic into L3). WhT2 traffic = 590 MB (L2-rate),
// adj streamed nontemporal (the 96us HBM fill floor), 18 independent loads
// in flight per iter. Mi = leaky(Wh1_i + max_j Wh2_j) >= row max =>
// exp <= 1, single pass. Writes UN-normalized partial C + S.
// ---------------------------------------------------------------------------
__global__ __launch_bounds__(64, 2) void k_attn(
    const int* __restrict__ adj,
    const _Float16* __restrict__ WhT2,
    const float* __restrict__ Wh1, const float* __restrict__ Wh2,
    const float* __restrict__ mxArr, int nmx,
    float* __restrict__ pC, float* __restrict__ pS)
{
    const int lane = threadIdx.x;
    const int m    = lane & 15;
    const int q    = lane >> 4;
    const int rowbase = blockIdx.x * 64;
    const int J    = gridDim.y;
    const int jy   = blockIdx.y;
    const int jlen = NN / J;
    const int jbeg = jy * jlen;

    const float mxv = wave_gmax(mxArr, nmx, lane);

    float wh1[4], Mi[4];
    const int* rowp[4];
    #pragma unroll
    for (int rg = 0; rg < 4; ++rg) {
        const int row = rowbase + rg * 16 + m;
        wh1[rg] = Wh1[row];
        const float tm = wh1[rg] + mxv;
        Mi[rg] = fmaxf(tm, ALPHA * tm);
        rowp[rg] = adj + (size_t)row * NN;
    }

    float4v c[4][8];
    #pragma unroll
    for (int rg = 0; rg < 4; ++rg)
        #pragma unroll
        for (int t = 0; t < 8; ++t) c[rg][t] = (float4v){0.f, 0.f, 0.f, 0.f};
    float S[4] = {0.f, 0.f, 0.f, 0.f};

    for (int j0 = jbeg; j0 < jbeg + jlen; j0 += 32) {
        const int jb = j0 + q * 8;

        // independent loads first: 8 adj + 8 frags + 2 Wh2
        int4v a0[4], a1[4];
        #pragma unroll
        for (int rg = 0; rg < 4; ++rg) {
            a0[rg] = __builtin_nontemporal_load((const int4v*)(rowp[rg] + jb));
            a1[rg] = __builtin_nontemporal_load((const int4v*)(rowp[rg] + jb + 4));
        }
        const _Float16* tp = WhT2 + (size_t)(j0 >> 5) * 4096;
        half8v b[8];
        #pragma unroll
        for (int t = 0; t < 8; ++t)
            b[t] = *(const half8v*)(tp + (t * 16 + m) * 32 + q * 8);
        const float4v w0 = *(const float4v*)(Wh2 + jb);
        const float4v w1 = *(const float4v*)(Wh2 + jb + 4);
        const float wvv[8] = {w0.x, w0.y, w0.z, w0.w, w1.x, w1.y, w1.z, w1.w};

        #pragma unroll
        for (int rg = 0; rg < 4; ++rg) {
            const half8v af = build_p(a0[rg], a1[rg], wvv, wh1[rg], Mi[rg], S[rg]);
            #pragma unroll
            for (int t = 0; t < 8; ++t)
                c[rg][t] = __builtin_amdgcn_mfma_f32_16x16x32_f16(af, b[t], c[rg][t], 0, 0, 0);
        }
    }

    #pragma unroll
    for (int rg = 0; rg < 4; ++rg) {
        S[rg] += __shfl_xor(S[rg], 16, 64);
        S[rg] += __shfl_xor(S[rg], 32, 64);
        if (q == 0) pS[(size_t)jy * NN + rowbase + rg * 16 + m] = S[rg];
    }

    #pragma unroll
    for (int rg = 0; rg < 4; ++rg)
        #pragma unroll
        for (int t = 0; t < 8; ++t)
            #pragma unroll
            for (int reg = 0; reg < 4; ++reg) {
                const int row = rowbase + rg * 16 + q * 4 + reg;
                pC[((size_t)jy * NN + row) * FOUT + t * 16 + m] = c[rg][t][reg];
            }
}

// ---------------------------------------------------------------------------
// Kernel 3: reduce J partials, normalize, ELU.
// ---------------------------------------------------------------------------
__global__ __launch_bounds__(256) void k_reduce(
    const float* __restrict__ pC, const float* __restrict__ pS,
    float* __restrict__ out, int J)
{
    const int idx = blockIdx.x * 256 + threadIdx.x;  // (row, col/4)
    const int row = idx >> 5;
    const int c4  = (idx & 31) * 4;
    float4v acc = (float4v){0.f, 0.f, 0.f, 0.f};
    float S = 0.f;
    for (int j = 0; j < J; ++j) {
        const float4v v = *(const float4v*)(pC + ((size_t)j * NN + row) * FOUT + c4);
        acc.x += v.x; acc.y += v.y; acc.z += v.z; acc.w += v.w;
        S += pS[(size_t)j * NN + row];
    }
    const float inv = 1.f / fmaxf(S, 1e-30f);
    float4v r;
    #pragma unroll
    for (int k = 0; k < 4; ++k) {
        const float v = acc[k] * inv;
        r[k] = (v > 0.f) ? v : (__expf(v) - 1.f);
    }
    *(float4v*)(out + (size_t)row * FOUT + c4) = r;
}

// ---------------------------------------------------------------------------
// Fallback (tiny ws): same structure, full j-range, direct epilogue.
// ---------------------------------------------------------------------------
__global__ __launch_bounds__(64, 2) void k_attn_fb(
    const int* __restrict__ adj,
    const _Float16* __restrict__ WhT2,
    const float* __restrict__ Wh1, const float* __restrict__ Wh2,
    const float* __restrict__ mxArr, int nmx,
    float* __restrict__ out)
{
    const int lane = threadIdx.x;
    const int m    = lane & 15;
    const int q    = lane >> 4;
    const int rowbase = blockIdx.x * 64;

    const float mxv = wave_gmax(mxArr, nmx, lane);

    float wh1[4], Mi[4];
    const int* rowp[4];
    #pragma unroll
    for (int rg = 0; rg < 4; ++rg) {
        const int row = rowbase + rg * 16 + m;
        wh1[rg] = Wh1[row];
        const float tm = wh1[rg] + mxv;
        Mi[rg] = fmaxf(tm, ALPHA * tm);
        rowp[rg] = adj + (size_t)row * NN;
    }

    float4v c[4][8];
    #pragma unroll
    for (int rg = 0; rg < 4; ++rg)
        #pragma unroll
        for (int t = 0; t < 8; ++t) c[rg][t] = (float4v){0.f, 0.f, 0.f, 0.f};
    float S[4] = {0.f, 0.f, 0.f, 0.f};

    for (int j0 = 0; j0 < NN; j0 += 32) {
        const int jb = j0 + q * 8;
        int4v a0[4], a1[4];
        #pragma unroll
        for (int rg = 0; rg < 4; ++rg) {
            a0[rg] = __builtin_nontemporal_load((const int4v*)(rowp[rg] + jb));
            a1[rg] = __builtin_nontemporal_load((const int4v*)(rowp[rg] + jb + 4));
        }
        const _Float16* tp = WhT2 + (size_t)(j0 >> 5) * 4096;
        half8v b[8];
        #pragma unroll
        for (int t = 0; t < 8; ++t)
            b[t] = *(const half8v*)(tp + (t * 16 + m) * 32 + q * 8);
        const float4v w0 = *(const float4v*)(Wh2 + jb);
        const float4v w1 = *(const float4v*)(Wh2 + jb + 4);
        const float wvv[8] = {w0.x, w0.y, w0.z, w0.w, w1.x, w1.y, w1.z, w1.w};
        #pragma unroll
        for (int rg = 0; rg < 4; ++rg) {
            const half8v af = build_p(a0[rg], a1[rg], wvv, wh1[rg], Mi[rg], S[rg]);
            #pragma unroll
            for (int t = 0; t < 8; ++t)
                c[rg][t] = __builtin_amdgcn_mfma_f32_16x16x32_f16(af, b[t], c[rg][t], 0, 0, 0);
        }
    }

    #pragma unroll
    for (int rg = 0; rg < 4; ++rg) {
        S[rg] += __shfl_xor(S[rg], 16, 64);
        S[rg] += __shfl_xor(S[rg], 32, 64);
        #pragma unroll
        for (int reg = 0; reg < 4; ++reg) {
            const int mloc = q * 4 + reg;
            const float Sr = __shfl(S[rg], mloc, 64);
            const float inv = 1.f / fmaxf(Sr, 1e-30f);
            #pragma unroll
            for (int t = 0; t < 8; ++t) {
                const float v = c[rg][t][reg] * inv;
                out[(size_t)(rowbase + rg * 16 + mloc) * FOUT + t * 16 + m] =
                    (v > 0.f) ? v : (__expf(v) - 1.f);
            }
        }
    }
}

// ---------------------------------------------------------------------------
extern "C" void kernel_launch(void* const* d_in, const int* in_sizes, int n_in,
                              void* d_out, int out_size, void* d_ws, size_t ws_size,
                              hipStream_t stream) {
    const float* h   = (const float*)d_in[0];
    const int*   adj = (const int*)d_in[1];
    const float* W   = (const float*)d_in[2];
    const float* a   = (const float*)d_in[3];
    float* out = (float*)d_out;

    char* ws = (char*)d_ws;
    float* Wh1   = (float*)ws;                          // 49152
    float* Wh2   = (float*)(ws + 49152);                // 49152
    float* mxArr = (float*)(ws + 98304);                // 768*4 = 3072
    _Float16* WhT2 = (_Float16*)(ws + 101376);          // 3,145,728
    const size_t base_need = 101376ULL + 3145728ULL;    // 3,247,104
    const int NB = NN / 16;                             // 768 k_wh blocks

    int J = 8;
    while (J > 1 &&
           base_need + (size_t)J * NN * 4 + (size_t)J * NN * FOUT * 4 > ws_size)
        J >>= 1;
    const bool ok =
        base_need + (size_t)NN * 4 + (size_t)NN * FOUT * 4 <= ws_size;

    k_wh<<<NB, 128, 0, stream>>>(h, W, a, WhT2, Wh1, Wh2, mxArr);
    if (ok) {
        float* pS = (float*)(ws + base_need);
        float* pC = pS + (size_t)J * NN;
        k_attn<<<dim3(NN / 64, J), 64, 0, stream>>>(adj, WhT2, Wh1, Wh2,
                                                    mxArr, NB, pC, pS);
        k_reduce<<<(NN * (FOUT / 4)) / 256, 256, 0, stream>>>(pC, pS, out, J);
    } else {
        k_attn_fb<<<NN / 64, 64, 0, stream>>>(adj, WhT2, Wh1, Wh2, mxArr, NB, out);
    }
}

// Round 9
// 930.705 us; speedup vs baseline: 1.1261x; 1.0915x over previous
//
#include <hip/hip_runtime.h>

#define NN   12288
#define FIN  256
#define FOUT 128
#define ALPHA 0.2f

typedef __attribute__((ext_vector_type(8))) _Float16 half8v;
typedef __attribute__((ext_vector_type(4))) float float4v;
typedef __attribute__((ext_vector_type(4))) int   int4v;

// WhT2 layout: [node>>5][feat 0..127][node&31]  (_Float16)
//   -> one j-tile (32 nodes x 128 feats) is a contiguous 8 KB block;
//      a wave's 8 B-fragment loads are each a coalesced 1 KB slice of it.

// ---------------------------------------------------------------------------
// Kernel 1: Wh = h @ W (fp32): WhT2 (f16 j-tiled) + Wh1/Wh2 (fp32) +
// per-block max of Wh2 -> mxArr[blockIdx]. One block = 16 nodes, 128 threads.
// ---------------------------------------------------------------------------
__global__ __launch_bounds__(128) void k_wh(
    const float* __restrict__ h,
    const float* __restrict__ W,
    const float* __restrict__ a,
    _Float16* __restrict__ WhT2,
    float* __restrict__ Wh1, float* __restrict__ Wh2,
    float* __restrict__ mxArr)
{
    __shared__ float sP1[2][16], sP2[2][16];
    const int t = threadIdx.x;                     // 0..127
    const int row0 = blockIdx.x * 16;

    float acc[16];
    #pragma unroll
    for (int r = 0; r < 16; ++r) acc[r] = 0.f;

    const float* hb = h + (size_t)row0 * FIN;
    for (int k = 0; k < FIN; k += 4) {
        const float w0 = W[(k + 0) * FOUT + t];
        const float w1 = W[(k + 1) * FOUT + t];
        const float w2 = W[(k + 2) * FOUT + t];
        const float w3 = W[(k + 3) * FOUT + t];
        #pragma unroll
        for (int r = 0; r < 16; ++r) {
            const float4v hv = *(const float4v*)(hb + r * FIN + k);  // uniform
            float s = acc[r];
            s = fmaf(hv.x, w0, s);
            s = fmaf(hv.y, w1, s);
            s = fmaf(hv.z, w2, s);
            s = fmaf(hv.w, w3, s);
            acc[r] = s;
        }
    }

    half8v pk0, pk1;
    #pragma unroll
    for (int r = 0; r < 8; ++r)  pk0[r] = (_Float16)acc[r];
    #pragma unroll
    for (int r = 0; r < 8; ++r)  pk1[r] = (_Float16)acc[8 + r];
    _Float16* dst = WhT2 + (size_t)(row0 >> 5) * 4096 + t * 32 + (row0 & 16);
    *(half8v*)(dst)     = pk0;
    *(half8v*)(dst + 8) = pk1;

    const float a1t = a[t];
    const float a2t = a[FOUT + t];
    const int lane = t & 63, wv = t >> 6;
    #pragma unroll
    for (int r = 0; r < 16; ++r) {
        float v1 = acc[r] * a1t;
        float v2 = acc[r] * a2t;
        #pragma unroll
        for (int off = 1; off < 64; off <<= 1) {
            v1 += __shfl_xor(v1, off, 64);
            v2 += __shfl_xor(v2, off, 64);
        }
        if (lane == 0) { sP1[wv][r] = v1; sP2[wv][r] = v2; }
    }
    __syncthreads();
    if (t < 16) {
        const float v1 = sP1[0][t] + sP1[1][t];
        float v2 = sP2[0][t] + sP2[1][t];
        Wh1[row0 + t] = v1;
        Wh2[row0 + t] = v2;
        #pragma unroll
        for (int off = 1; off < 16; off <<= 1)
            v2 = fmaxf(v2, __shfl_xor(v2, off, 64));
        if (t == 0) mxArr[blockIdx.x] = v2;
    }
}

// ---------------------------------------------------------------------------
// P-fragment builder: leaky -> mask -> exp(e-M); f16 numerator, f32 row sum.
// ---------------------------------------------------------------------------
static __device__ __forceinline__ half8v build_p(
    const int4v a0, const int4v a1, const float* wvv,
    const float wh1, const float M, float& S)
{
    const int av[8] = {a0.x, a0.y, a0.z, a0.w, a1.x, a1.y, a1.z, a1.w};
    half8v af;
    #pragma unroll
    for (int jj = 0; jj < 8; ++jj) {
        float e = wh1 + wvv[jj];
        e = fmaxf(e, ALPHA * e);
        const float p = av[jj] ? __expf(e - M) : 0.f;
        af[jj] = (_Float16)p;
        S += p;
    }
    return af;
}

// wave-level global max over per-block maxima (single-wave block, no LDS)
static __device__ __forceinline__ float wave_gmax(
    const float* __restrict__ mxArr, int nmx, int lane)
{
    float mv = -1e30f;
    for (int idx = lane; idx < nmx; idx += 64) mv = fmaxf(mv, mxArr[idx]);
    #pragma unroll
    for (int off = 1; off < 64; off <<= 1)
        mv = fmaxf(mv, __shfl_xor(mv, off, 64));
    return mv;
}

// ---------------------------------------------------------------------------
// Kernel 2: fused masked-softmax attention + PV GEMM (partials).
// Grid (NN/32, J); block = ONE wave, no LDS, no barriers. Wave owns 32 rows
// as 2 row-groups of 16; B-fragments loaded once per 32-j tile, reused by
// both row-groups (register-level reuse; R7 lesson). R8 lesson: 4 row-groups
// cost ~240 VGPRs -> no software pipelining + 6 waves/CU -> latency-bound.
// Now: ~160 VGPRs (3 waves/SIMD), 3072 waves = 12/CU, and the adj octets
// (the ~900cy HBM stream) are EXPLICITLY double-buffered in registers:
// next iter's 4 adj loads issue before this iter's compute. WhT2 frags are
// just-in-time (L2-hot; adj nt loads don't evict). Mi = leaky(Wh1_i +
// max_j Wh2_j) >= row max => exp<=1, single pass. Writes partial C + S.
// ---------------------------------------------------------------------------
__global__ __launch_bounds__(64, 2) void k_attn(
    const int* __restrict__ adj,
    const _Float16* __restrict__ WhT2,
    const float* __restrict__ Wh1, const float* __restrict__ Wh2,
    const float* __restrict__ mxArr, int nmx,
    float* __restrict__ pC, float* __restrict__ pS)
{
    const int lane = threadIdx.x;
    const int m    = lane & 15;
    const int q    = lane >> 4;
    const int rowbase = blockIdx.x * 32;
    const int J    = gridDim.y;
    const int jy   = blockIdx.y;
    const int jlen = NN / J;
    const int jbeg = jy * jlen;

    const float mxv = wave_gmax(mxArr, nmx, lane);

    float wh1[2], Mi[2];
    const int* rowp[2];
    #pragma unroll
    for (int rg = 0; rg < 2; ++rg) {
        const int row = rowbase + rg * 16 + m;
        wh1[rg] = Wh1[row];
        const float tm = wh1[rg] + mxv;
        Mi[rg] = fmaxf(tm, ALPHA * tm);
        rowp[rg] = adj + (size_t)row * NN;
    }

    float4v c[2][8];
    #pragma unroll
    for (int rg = 0; rg < 2; ++rg)
        #pragma unroll
        for (int t = 0; t < 8; ++t) c[rg][t] = (float4v){0.f, 0.f, 0.f, 0.f};
    float S[2] = {0.f, 0.f};

    // prologue: prefetch iter 0's adj + Wh2 into the "next" registers
    int4v na0[2], na1[2];
    float4v nw0, nw1;
    {
        const int jb = jbeg + q * 8;
        #pragma unroll
        for (int rg = 0; rg < 2; ++rg) {
            na0[rg] = __builtin_nontemporal_load((const int4v*)(rowp[rg] + jb));
            na1[rg] = __builtin_nontemporal_load((const int4v*)(rowp[rg] + jb + 4));
        }
        nw0 = *(const float4v*)(Wh2 + jb);
        nw1 = *(const float4v*)(Wh2 + jb + 4);
    }

    const int iters = jlen / 32;
    for (int it = 0; it < iters; ++it) {
        const int j0 = jbeg + it * 32;

        // rotate prefetched -> current
        const int4v a0[2] = {na0[0], na0[1]};
        const int4v a1[2] = {na1[0], na1[1]};
        const float4v w0 = nw0, w1 = nw1;

        // prefetch next iteration's adj + Wh2 (the HBM-latency stream)
        if (it + 1 < iters) {
            const int jb = j0 + 32 + q * 8;
            #pragma unroll
            for (int rg = 0; rg < 2; ++rg) {
                na0[rg] = __builtin_nontemporal_load((const int4v*)(rowp[rg] + jb));
                na1[rg] = __builtin_nontemporal_load((const int4v*)(rowp[rg] + jb + 4));
            }
            nw0 = *(const float4v*)(Wh2 + jb);
            nw1 = *(const float4v*)(Wh2 + jb + 4);
        }

        // B fragments just-in-time from L2 (8 KB tile, coalesced 1 KB each)
        const _Float16* tp = WhT2 + (size_t)(j0 >> 5) * 4096;
        half8v b[8];
        #pragma unroll
        for (int t = 0; t < 8; ++t)
            b[t] = *(const half8v*)(tp + (t * 16 + m) * 32 + q * 8);

        const float wvv[8] = {w0.x, w0.y, w0.z, w0.w, w1.x, w1.y, w1.z, w1.w};

        #pragma unroll
        for (int rg = 0; rg < 2; ++rg) {
            const half8v af = build_p(a0[rg], a1[rg], wvv, wh1[rg], Mi[rg], S[rg]);
            #pragma unroll
            for (int t = 0; t < 8; ++t)
                c[rg][t] = __builtin_amdgcn_mfma_f32_16x16x32_f16(af, b[t], c[rg][t], 0, 0, 0);
        }
    }

    #pragma unroll
    for (int rg = 0; rg < 2; ++rg) {
        S[rg] += __shfl_xor(S[rg], 16, 64);
        S[rg] += __shfl_xor(S[rg], 32, 64);
        if (q == 0) pS[(size_t)jy * NN + rowbase + rg * 16 + m] = S[rg];
    }

    #pragma unroll
    for (int rg = 0; rg < 2; ++rg)
        #pragma unroll
        for (int t = 0; t < 8; ++t)
            #pragma unroll
            for (int reg = 0; reg < 4; ++reg) {
                const int row = rowbase + rg * 16 + q * 4 + reg;
                pC[((size_t)jy * NN + row) * FOUT + t * 16 + m] = c[rg][t][reg];
            }
}

// ---------------------------------------------------------------------------
// Kernel 3: reduce J partials, normalize, ELU.
// ---------------------------------------------------------------------------
__global__ __launch_bounds__(256) void k_reduce(
    const float* __restrict__ pC, const float* __restrict__ pS,
    float* __restrict__ out, int J)
{
    const int idx = blockIdx.x * 256 + threadIdx.x;  // (row, col/4)
    const int row = idx >> 5;
    const int c4  = (idx & 31) * 4;
    float4v acc = (float4v){0.f, 0.f, 0.f, 0.f};
    float S = 0.f;
    for (int j = 0; j < J; ++j) {
        const float4v v = *(const float4v*)(pC + ((size_t)j * NN + row) * FOUT + c4);
        acc.x += v.x; acc.y += v.y; acc.z += v.z; acc.w += v.w;
        S += pS[(size_t)j * NN + row];
    }
    const float inv = 1.f / fmaxf(S, 1e-30f);
    float4v r;
    #pragma unroll
    for (int k = 0; k < 4; ++k) {
        const float v = acc[k] * inv;
        r[k] = (v > 0.f) ? v : (__expf(v) - 1.f);
    }
    *(float4v*)(out + (size_t)row * FOUT + c4) = r;
}

// ---------------------------------------------------------------------------
// Fallback (tiny ws): same structure, full j-range, direct epilogue.
// ---------------------------------------------------------------------------
__global__ __launch_bounds__(64, 2) void k_attn_fb(
    const int* __restrict__ adj,
    const _Float16* __restrict__ WhT2,
    const float* __restrict__ Wh1, const float* __restrict__ Wh2,
    const float* __restrict__ mxArr, int nmx,
    float* __restrict__ out)
{
    const int lane = threadIdx.x;
    const int m    = lane & 15;
    const int q    = lane >> 4;
    const int rowbase = blockIdx.x * 32;

    const float mxv = wave_gmax(mxArr, nmx, lane);

    float wh1[2], Mi[2];
    const int* rowp[2];
    #pragma unroll
    for (int rg = 0; rg < 2; ++rg) {
        const int row = rowbase + rg * 16 + m;
        wh1[rg] = Wh1[row];
        const float tm = wh1[rg] + mxv;
        Mi[rg] = fmaxf(tm, ALPHA * tm);
        rowp[rg] = adj + (size_t)row * NN;
    }

    float4v c[2][8];
    #pragma unroll
    for (int rg = 0; rg < 2; ++rg)
        #pragma unroll
        for (int t = 0; t < 8; ++t) c[rg][t] = (float4v){0.f, 0.f, 0.f, 0.f};
    float S[2] = {0.f, 0.f};

    for (int j0 = 0; j0 < NN; j0 += 32) {
        const int jb = j0 + q * 8;
        int4v a0[2], a1[2];
        #pragma unroll
        for (int rg = 0; rg < 2; ++rg) {
            a0[rg] = __builtin_nontemporal_load((const int4v*)(rowp[rg] + jb));
            a1[rg] = __builtin_nontemporal_load((const int4v*)(rowp[rg] + jb + 4));
        }
        const _Float16* tp = WhT2 + (size_t)(j0 >> 5) * 4096;
        half8v b[8];
        #pragma unroll
        for (int t = 0; t < 8; ++t)
            b[t] = *(const half8v*)(tp + (t * 16 + m) * 32 + q * 8);
        const float4v w0 = *(const float4v*)(Wh2 + jb);
        const float4v w1 = *(const float4v*)(Wh2 + jb + 4);
        const float wvv[8] = {w0.x, w0.y, w0.z, w0.w, w1.x, w1.y, w1.z, w1.w};
        #pragma unroll
        for (int rg = 0; rg < 2; ++rg) {
            const half8v af = build_p(a0[rg], a1[rg], wvv, wh1[rg], Mi[rg], S[rg]);
            #pragma unroll
            for (int t = 0; t < 8; ++t)
                c[rg][t] = __builtin_amdgcn_mfma_f32_16x16x32_f16(af, b[t], c[rg][t], 0, 0, 0);
        }
    }

    #pragma unroll
    for (int rg = 0; rg < 2; ++rg) {
        S[rg] += __shfl_xor(S[rg], 16, 64);
        S[rg] += __shfl_xor(S[rg], 32, 64);
        #pragma unroll
        for (int reg = 0; reg < 4; ++reg) {
            const int mloc = q * 4 + reg;
            const float Sr = __shfl(S[rg], mloc, 64);
            const float inv = 1.f / fmaxf(Sr, 1e-30f);
            #pragma unroll
            for (int t = 0; t < 8; ++t) {
                const float v = c[rg][t][reg] * inv;
                out[(size_t)(rowbase + rg * 16 + mloc) * FOUT + t * 16 + m] =
                    (v > 0.f) ? v : (__expf(v) - 1.f);
            }
        }
    }
}

// ---------------------------------------------------------------------------
extern "C" void kernel_launch(void* const* d_in, const int* in_sizes, int n_in,
                              void* d_out, int out_size, void* d_ws, size_t ws_size,
                              hipStream_t stream) {
    const float* h   = (const float*)d_in[0];
    const int*   adj = (const int*)d_in[1];
    const float* W   = (const float*)d_in[2];
    const float* a   = (const float*)d_in[3];
    float* out = (float*)d_out;

    char* ws = (char*)d_ws;
    float* Wh1   = (float*)ws;                          // 49152
    float* Wh2   = (float*)(ws + 49152);                // 49152
    float* mxArr = (float*)(ws + 98304);                // 768*4 = 3072
    _Float16* WhT2 = (_Float16*)(ws + 101376);          // 3,145,728
    const size_t base_need = 101376ULL + 3145728ULL;    // 3,247,104
    const int NB = NN / 16;                             // 768 k_wh blocks

    int J = 8;
    while (J > 1 &&
           base_need + (size_t)J * NN * 4 + (size_t)J * NN * FOUT * 4 > ws_size)
        J >>= 1;
    const bool ok =
        base_need + (size_t)NN * 4 + (size_t)NN * FOUT * 4 <= ws_size;

    k_wh<<<NB, 128, 0, stream>>>(h, W, a, WhT2, Wh1, Wh2, mxArr);
    if (ok) {
        float* pS = (float*)(ws + base_need);
        float* pC = pS + (size_t)J * NN;
        k_attn<<<dim3(NN / 32, J), 64, 0, stream>>>(adj, WhT2, Wh1, Wh2,
                                                    mxArr, NB, pC, pS);
        k_reduce<<<(NN * (FOUT / 4)) / 256, 256, 0, stream>>>(pC, pS, out, J);
    } else {
        k_attn_fb<<<NN / 32, 64, 0, stream>>>(adj, WhT2, Wh1, Wh2, mxArr, NB, out);
    }
}